// Round 8
// baseline (179.866 us; speedup 1.0000x reference)
//
#include <hip/hip_runtime.h>
#include <cstdint>
#include <cstddef>

typedef unsigned long long ull;
typedef __bf16 bf16x8 __attribute__((ext_vector_type(8)));
typedef float f32x4 __attribute__((ext_vector_type(4)));

#define NA     147456   // 128*128*9 anchors
#define NT     64       // targets
#define KDIM   4608     // 512*9 reduction
#define NTASK  1280     // 128*6 + 256*2 output-value tasks
#define CAND_CAP 4096
#define NIOUB  576      // iou blocks (k_pi [0,576))
#define NPREPB 512      // prep blocks, one per cout row (k_pi [576,1088))

// ---- workspace byte offsets (~28.8 MB) ----
#define OFF_WB2   0           // ushort[576*512*8]  bf16 weights, frag-native [kc][m][8], k = r*512+cin
#define OFF_P2    4718592     // ushort[576*1280*8] bf16 im2col,  frag-native [kc][t][8]
#define OFF_H4    16515072    // float[4][1280][512] K-split partial h, task-major
#define OFF_MIOU  27000832    // float[147456]
#define OFF_CAND  27590656    // ull[576*256] block-local candidate lists
#define OFF_CPB   28770304    // int[576] per-block candidate counts
#define OFF_CBZ   28772608    // int[576] per-block zero-iou counts
#define OFF_NPOS  28774912    // int
#define OFF_TREG  28774920    // float[512]
#define OFF_TASKS 28776968    // int[1280]
#define OFF_RUNS  28782088    // int[512] gather-run table
#define OFF_OUT   28784136    // float[1280]

// anchor w/h table; U = sqrt(128*128/2); power-of-2 multiples are exact in fp32.
#define UANC 90.509667991878f
__device__ __constant__ float WKa[9] = {128.0f, 2.0f*UANC, UANC, 256.0f, 4.0f*UANC, 2.0f*UANC, 512.0f, 8.0f*UANC, 4.0f*UANC};
__device__ __constant__ float HKa[9] = {128.0f, UANC, 2.0f*UANC, 256.0f, 2.0f*UANC, 4.0f*UANC, 512.0f, 4.0f*UANC, 8.0f*UANC};

__device__ __forceinline__ float iou_one(float x1, float y1, float x2, float y2, float4 t) {
#pragma clang fp contract(off)
  float ltx = fmaxf(t.x, x1), lty = fmaxf(t.y, y1);
  float rbx = fminf(t.z, x2), rby = fminf(t.w, y2);
  float wx = fmaxf(rbx - ltx, 0.0f);
  float wy = fmaxf(rby - lty, 0.0f);
  float inter = wx * wy;
  float at = (t.z - t.x) * (t.w - t.y);
  float aa = (x2 - x1) * (y2 - y1);
  return inter / ((at + aa) - inter);
}

__device__ __forceinline__ unsigned short f2bf(float f) {
  unsigned int u = __float_as_uint(f);
  unsigned int r = (u + 0x7fffu + ((u >> 16) & 1u)) >> 16;
  return (unsigned short)r;
}

// [0,576): IoU + per-block candidate/zero stats; [576,1088): weight repack
__global__ __launch_bounds__(256) void k_pi(const float* __restrict__ cw,
    unsigned short* __restrict__ Wb2,
    const float* __restrict__ tgt, const int* __restrict__ imw,
    const int* __restrict__ imh, float* __restrict__ miou,
    ull* __restrict__ cand, int* __restrict__ cpb, int* __restrict__ cbz) {
  __shared__ __align__(16) char smem[20480];
  int blk = blockIdx.x;
  int tid = threadIdx.x;
  if (blk >= NIOUB) {                          // ---- prep: one cout row, LDS-staged ----
    float* row = (float*)smem;                 // padded [cin*10 + r]
    int m = blk - NIOUB;
    const float* src = cw + (size_t)m * KDIM;
    for (int f = tid; f < KDIM; f += 256) {
      int cin = f / 9;
      row[cin * 10 + (f - cin * 9)] = src[f];  // coalesced global read
    }
    __syncthreads();
    for (int kc = tid; kc < 576; kc += 256) {
      int r = kc >> 6, c8 = kc & 63;
      int base = c8 * 80 + r;
      unsigned short o[8];
      #pragma unroll
      for (int j = 0; j < 8; ++j) o[j] = f2bf(row[base + j * 10]);
      *(uint4*)(Wb2 + ((size_t)kc * 512 + m) * 8) = *(const uint4*)o;
    }
    return;
  }
  // ---- IoU ----
  float4* ts = (float4*)smem;                  // [64]
  int* wz = (int*)(smem + 1024);
  int* wc = wz + 4;
  if (tid < NT) ts[tid] = ((const float4*)tgt)[tid];
  __syncthreads();
  int a = blk * 256 + tid;
  int k = a % 9;
  int pq = a / 9;
  int p = pq >> 7, q = pq & 127;
  float dx = (float)(*imw) / 127.0f;
  float dyl = (float)(*imh) / 127.0f;
  float x1 = (float)p * dx, y1 = (float)q * dyl;
  float x2 = x1 + WKa[k], y2 = y1 + HKa[k];
  float best = -1.0f;
  #pragma unroll 8
  for (int t = 0; t < NT; ++t) best = fmaxf(best, iou_one(x1, y1, x2, y2, ts[t]));
  miou[a] = best;
  int lane = tid & 63, w = tid >> 6;
  ull bz = __ballot(best == 0.0f);
  bool isc = best > 0.7f;
  ull bc = __ballot(isc);
  if (lane == 0) { wz[w] = (int)__popcll(bz); wc[w] = (int)__popcll(bc); }
  __syncthreads();
  if (tid == 0) {
    cbz[blk] = wz[0] + wz[1] + wz[2] + wz[3];
    cpb[blk] = wc[0] + wc[1] + wc[2] + wc[3];
  }
  if (isc) {
    int woff = 0;
    for (int i = 0; i < w; ++i) woff += wc[i];
    int rank = woff + (int)__popcll(bc & ((1ull << lane) - 1ull));
    cand[blk * 256 + rank] = ((ull)__float_as_uint(best) << 32) | (ull)(0xFFFFFFFFu - (unsigned)a);
  }
}

// single block: pos top-128 SET via radix-select + neg-select + treg + tasks + runs
__global__ __launch_bounds__(256) void k_sel(const float* __restrict__ miou,
    const ull* __restrict__ cand, const int* __restrict__ cpb,
    const int* __restrict__ cbz, const float* __restrict__ tgt,
    const int* __restrict__ imw, const int* __restrict__ imh,
    int* __restrict__ nposp, float* __restrict__ treg, int* __restrict__ tasks,
    int* __restrict__ runs) {
  __shared__ ull keys[CAND_CAP];               // 32 KB
  __shared__ ull bnd[1024];                    // 8 KB
  __shared__ int hist[1024];                   // 4 KB
  __shared__ int cpbL[576];
  __shared__ int base576[577];
  __shared__ int nzbase[145];
  __shared__ float4 ts[NT];
  __shared__ int posi[128];
  __shared__ int negA[256];
  __shared__ int wtot[4];
  __shared__ int wsum[4];
  __shared__ int selCnt, bndCnt, Tbin, mAbove;
  int tid = threadIdx.x;
  int lane = tid & 63;
  if (tid < NT) ts[tid] = ((const float4*)tgt)[tid];
  for (int i = tid; i < 576; i += 256) cpbL[i] = cpb[i];
  for (int i = tid; i < 1024; i += 256) hist[i] = 0;
  __syncthreads();
  // ---- scan A: exclusive prefix over cpbL[576] ----
  int e0 = 0, e1 = 0, sA = 0, scanA = 0;
  if (tid < 192) {
    e0 = cpbL[3 * tid]; e1 = cpbL[3 * tid + 1]; int e2 = cpbL[3 * tid + 2];
    sA = e0 + e1 + e2;
    scanA = sA;
    for (int off = 1; off < 64; off <<= 1) {
      int v = __shfl_up(scanA, off);
      if (lane >= off) scanA += v;
    }
    if (lane == 63) wtot[tid >> 6] = scanA;
  }
  // ---- scan B: per-1024-chunk zero counts ----
  int sB = 0, scanB = 0;
  if (tid < 144) {
    int4 cz4 = *(const int4*)(cbz + 4 * tid);
    sB = cz4.x + cz4.y + cz4.z + cz4.w;
    scanB = sB;
    for (int off = 1; off < 64; off <<= 1) {
      int v = __shfl_up(scanB, off);
      if (lane >= off) scanB += v;
    }
    bool last = (tid < 128) ? (lane == 63) : (tid == 143);
    if (last) wsum[tid >> 6] = scanB;
  }
  __syncthreads();
  if (tid < 192) {
    int w = tid >> 6;
    int woff = 0;
    for (int i = 0; i < w; ++i) woff += wtot[i];
    int excl = woff + scanA - sA;
    base576[3 * tid]     = excl;
    base576[3 * tid + 1] = excl + e0;
    base576[3 * tid + 2] = excl + e0 + e1;
    if (tid == 191) base576[576] = excl + sA;
  }
  if (tid < 144) {
    int w = tid >> 6;
    int woff = 0;
    for (int i = 0; i < w; ++i) woff += wsum[i];
    nzbase[tid] = woff + scanB - sB;
    if (tid == 143) nzbase[144] = woff + scanB;
  }
  __syncthreads();
  int cnt = base576[576]; if (cnt > CAND_CAP) cnt = CAND_CAP;
  for (int i = tid; i < CAND_CAP; i += 256) if (i >= cnt) keys[i] = 0ull;
  // load-balanced compaction: rank -> (block,entry) via binary search
  for (int rk = tid; rk < cnt; rk += 256) {
    int lo = 0, hi = 576;
    while (hi - lo > 1) { int mid = (lo + hi) >> 1; if (base576[mid] <= rk) lo = mid; else hi = mid; }
    keys[rk] = cand[lo * 256 + (rk - base576[lo])];
  }
  __syncthreads();
  int np;
  if (cnt <= 128) {                            // set-invariant: slot order irrelevant
    np = cnt;
    if (tid < cnt) posi[tid] = (int)(0xFFFFFFFFu - (unsigned)(keys[tid] & 0xFFFFFFFFull));
  } else {
    np = 128;
    // histogram of iou high bits: bin = (bits-0x3F333334)>>13 in [0,614]
    for (int i = tid; i < cnt; i += 256) {
      unsigned ib = (unsigned)(keys[i] >> 32);
      atomicAdd(&hist[(ib - 0x3F333334u) >> 13], 1);
    }
    __syncthreads();
    if (tid < 64) {                            // coarse suffix scan -> threshold bin
      int s = 0;
      #pragma unroll
      for (int t = 0; t < 16; ++t) s += hist[tid * 16 + t];
      int S = s;
      #pragma unroll
      for (int off = 1; off < 64; off <<= 1) {
        int u = __shfl_down(S, off);
        if (tid + off < 64) S += u;
      }
      ull mask = __ballot(S >= 128);
      int g = 63 - __clzll(mask);
      int aboveS = __shfl(S, (g + 1 < 64) ? g + 1 : 63);
      if (g == 63) aboveS = 0;
      if (tid == 0) {
        int run = aboveS, T = g * 16 + 15;
        for (int b = g * 16 + 15; b >= g * 16; --b) {
          int h = hist[b];
          if (run + h >= 128) { T = b; break; }
          run += h;
        }
        Tbin = T; mAbove = run; selCnt = 0; bndCnt = 0;
      }
    }
    __syncthreads();
    int T = Tbin, m = mAbove;
    for (int i = tid; i < cnt; i += 256) {
      ull kk = keys[i];
      unsigned ib = (unsigned)(kk >> 32);
      int b = (int)((ib - 0x3F333334u) >> 13);
      if (b > T) {
        int r = atomicAdd(&selCnt, 1);
        posi[r] = (int)(0xFFFFFFFFu - (unsigned)(kk & 0xFFFFFFFFull));
      } else if (b == T) {
        int r = atomicAdd(&bndCnt, 1);
        if (r < 1024) bnd[r] = kk;
      }
    }
    __syncthreads();
    int B = bndCnt;
    int need = 128 - m;
    if (B <= 1024) {
      int n2 = 2; while (n2 < B) n2 <<= 1;
      for (int i = tid; i < n2; i += 256) if (i >= B) bnd[i] = 0ull;
      for (int size = 2; size <= n2; size <<= 1)
        for (int stride = size >> 1; stride > 0; stride >>= 1) {
          __syncthreads();
          for (int t = tid; t < n2 / 2; t += 256) {
            int i = 2 * t - (t & (stride - 1));
            int j = i + stride;
            ull a = bnd[i], b2 = bnd[j];
            bool desc = ((i & size) == 0);
            if (desc ? (a < b2) : (a > b2)) { bnd[i] = b2; bnd[j] = a; }
          }
        }
      __syncthreads();
      if (tid < need) posi[m + tid] = (int)(0xFFFFFFFFu - (unsigned)(bnd[tid] & 0xFFFFFFFFull));
    } else {                                   // pathological tie storm: full sort fallback
      for (int size = 2; size <= CAND_CAP; size <<= 1)
        for (int stride = size >> 1; stride > 0; stride >>= 1) {
          __syncthreads();
          for (int t = tid; t < CAND_CAP / 2; t += 256) {
            int i = 2 * t - (t & (stride - 1));
            int j = i + stride;
            ull a = keys[i], b2 = keys[j];
            bool desc = ((i & size) == 0);
            if (desc ? (a < b2) : (a > b2)) { keys[i] = b2; keys[j] = a; }
          }
        }
      __syncthreads();
      if (tid < 128) posi[tid] = (int)(0xFFFFFFFFu - (unsigned)(keys[tid] & 0xFFFFFFFFull));
    }
  }
  if (tid == 0) *nposp = np;
  __syncthreads();
  // ---- neg select: first 256 zero-iou anchors by index ----
  int w = tid >> 6;
  for (int j = 0; j < 144; ++j) {
    if (nzbase[j] >= 256) break;               // uniform
    int a0 = j * 1024 + tid * 4;
    float4 m4 = *(const float4*)(miou + a0);
    int f0 = (m4.x == 0.0f), f1 = (m4.y == 0.0f), f2 = (m4.z == 0.0f), f3 = (m4.w == 0.0f);
    int tsum = f0 + f1 + f2 + f3;
    int scan = tsum;
    for (int off = 1; off < 64; off <<= 1) {
      int v = __shfl_up(scan, off);
      if (lane >= off) scan += v;
    }
    if (lane == 63) wsum[w] = scan;
    __syncthreads();
    int woff = nzbase[j];
    for (int i = 0; i < w; ++i) woff += wsum[i];
    int r = woff + scan - tsum;
    if (f0) { if (r < 256) negA[r] = a0;     r++; }
    if (f1) { if (r < 256) negA[r] = a0 + 1; r++; }
    if (f2) { if (r < 256) negA[r] = a0 + 2; r++; }
    if (f3) { if (r < 256) negA[r] = a0 + 3;      }
    __syncthreads();
  }
  __syncthreads();
  // ---- treg for pos anchors ----
  if (tid < np) {
    int a = posi[tid];
    int k = a % 9; int pq = a / 9; int p = pq >> 7, q = pq & 127;
    float dx = (float)(*imw) / 127.0f, dyl = (float)(*imh) / 127.0f;
    float x1 = (float)p * dx, y1 = (float)q * dyl;
    float x2 = x1 + WKa[k], y2 = y1 + HKa[k];
    float best = -1.0f; int bt = 0;
    for (int t = 0; t < NT; ++t) {
      float v = iou_one(x1, y1, x2, y2, ts[t]);
      if (v > best) { best = v; bt = t; }      // first-max == jnp.argmax
    }
    float4 m = ts[bt];
    float aw = x2 - x1, ah = y2 - y1;
    float acx = x1 + aw * 0.5f, acy = y1 + ah * 0.5f;
    float bwd = m.z - m.x, bhd = m.w - m.y;
    float bcx = m.x + bwd * 0.5f, bcy = m.y + bhd * 0.5f;
    treg[tid * 4 + 0] = (bcx - acx) / aw;
    treg[tid * 4 + 1] = (bcy - acy) / ah;
    treg[tid * 4 + 2] = logf(bwd / aw);
    treg[tid * 4 + 3] = logf(bhd / ah);
  }
  // ---- task table (for k_out/k_loss) ----
  for (int t = tid; t < NTASK; t += 256) {
    int rec = 0;
    if (t < 768) {
      int s = t / 6, jj = t - s * 6;
      if (s < np) {
        int a = posi[s];
        int f, wr, xx;
        if (jj < 4) { f = 4 * a; wr = f >> 14; xx = (f & 127) + jj; }
        else        { f = 2 * a; wr = 36 + (f >> 14); xx = (f & 127) + (jj - 4); }
        int yy = (f >> 7) & 127;
        rec = (int)(0x80000000u | ((unsigned)wr << 16) | ((unsigned)yy << 8) | (unsigned)xx);
      }
    } else {
      int s = (t - 768) >> 1, jj = (t - 768) & 1;
      if (s < 256 - np) {
        int a = negA[s];
        int f = 2 * a; int wr = 36 + (f >> 14); int yy = (f >> 7) & 127; int xx = (f & 127) + jj;
        rec = (int)(0x80000000u | ((unsigned)wr << 16) | ((unsigned)yy << 8) | (unsigned)xx);
      }
    }
    tasks[t] = rec;
  }
  // ---- run table for k_gather: valid<<31 | wide<<25 | task_base<<14 | py<<7 | px ----
  for (int s2 = tid; s2 < 512; s2 += 256) {
    int rec;
    if (s2 < 256) {                            // pos: s = s2>>1; even=bbox(4 tasks), odd=score(2)
      int s = s2 >> 1;
      int odd = s2 & 1;
      int tb = 6 * s + (odd ? 4 : 0);
      int wide = odd ? 0 : (1 << 25);
      if (s < np) {
        int a = posi[s];
        int f = odd ? 2 * a : 4 * a;
        rec = (int)(0x80000000u | (unsigned)wide | ((unsigned)tb << 14) |
                    ((unsigned)((f >> 7) & 127) << 7) | (unsigned)(f & 127));
      } else {
        rec = wide | (tb << 14);               // invalid: zero-fill its tasks
      }
    } else {                                   // neg: 2 tasks each
      int s = s2 - 256;
      int tb = 768 + 2 * s;
      if (s < 256 - np) {
        int a = negA[s];
        int f = 2 * a;
        rec = (int)(0x80000000u | ((unsigned)tb << 14) |
                    ((unsigned)((f >> 7) & 127) << 7) | (unsigned)(f & 127));
      } else {
        rec = tb << 14;
      }
    }
    runs[s2] = rec;
  }
}

// targeted gather-im2col: one block per run; 3x<=6 patch x 512 cin -> LDS bf16 ->
// fragment-native P2 writes. Replaces the full NHWC transpose + separate im2col.
__global__ __launch_bounds__(256) void k_gather(const float* __restrict__ x,
    const int* __restrict__ runs, unsigned short* __restrict__ P2) {
  __shared__ __align__(16) unsigned short L[3 * 6 * 520];   // [dy][col][cin], cin padded
  int tid = threadIdx.x;
  int rec = runs[blockIdx.x];
  int wide = (rec >> 25) & 1;
  int ntasks = wide ? 4 : 2;
  int tb = (rec >> 14) & 2047;
  int total = 576 * ntasks;
  if (rec >= 0) {                              // invalid run: zero its tasks' P2
    uint4 z = {0, 0, 0, 0};
    for (int w = tid; w < total; w += 256) {
      int kc, lt;
      if (wide) { kc = w >> 2; lt = w & 3; } else { kc = w >> 1; lt = w & 1; }
      *(uint4*)(P2 + ((size_t)kc * NTASK + tb + lt) * 8) = z;
    }
    return;
  }
  int py = (rec >> 7) & 127, px = rec & 127;
  // load phase: thread handles 2 consecutive cin x one dy row, 6 cols
  #pragma unroll
  for (int i = 0; i < 3; ++i) {
    int pair = i * 256 + tid;                  // 768 pairs
    int cin = (pair & 255) * 2;
    int dy = pair >> 8;
    int row = py + dy - 1;
    bool rowok = (row >= 0) && (row < 128);
    const float* s0 = x + (size_t)cin * 16384 + row * 128;
    const float* s1 = s0 + 16384;
    #pragma unroll
    for (int c = 0; c < 6; ++c) {
      int xx = px - 1 + c;
      bool ok = rowok && (xx >= 0) && (xx < 128);
      float v0 = ok ? s0[xx] : 0.0f;
      float v1 = ok ? s1[xx] : 0.0f;
      unsigned pk = ((unsigned)f2bf(v1) << 16) | (unsigned)f2bf(v0);
      *(unsigned*)&L[(dy * 6 + c) * 520 + cin] = pk;
    }
  }
  __syncthreads();
  // write phase: fragment per (kc, local task)
  for (int w = tid; w < total; w += 256) {
    int kc, lt;
    if (wide) { kc = w >> 2; lt = w & 3; } else { kc = w >> 1; lt = w & 1; }
    int r = kc >> 6, c8 = kc & 63;
    int dy = r / 3, dxp = r - dy * 3;
    int col = lt + dxp;
    uint4 frag = *(const uint4*)&L[(dy * 6 + col) * 520 + c8 * 8];
    *(uint4*)(P2 + ((size_t)kc * NTASK + tb + lt) * 8) = frag;
  }
}

// LDS-free bf16 MFMA GEMM: 64x64 tile per WAVE, 4 waves of a block = 4 K-splits
// of the same tile, each writing its own H4 slice. grid (20 t-tiles, 8 c-tiles).
__global__ __launch_bounds__(256) void k_mfma(const unsigned short* __restrict__ Wb2,
    const unsigned short* __restrict__ P2, const int* __restrict__ nposp,
    float* __restrict__ H4) {
  int npos = *nposp;
  int tt0 = blockIdx.x * 64;
  int posend = 6 * npos, negend = 768 + 2 * (256 - npos);
  if (!((tt0 < posend) || ((tt0 + 64 > 768) && (tt0 < negend)))) return;
  int c0 = blockIdx.y * 64;
  int tid = threadIdx.x;
  int wave = tid >> 6, lane = tid & 63;
  int quad = lane >> 4, r = lane & 15;
  int kc0 = wave * 144 + quad;                 // wave = K-split
  const bf16x8* Ab = (const bf16x8*)Wb2 + ((size_t)kc0 * 512 + c0 + r);
  const bf16x8* Bb = (const bf16x8*)P2 + ((size_t)kc0 * NTASK + tt0 + r);

  f32x4 acc[4][4];
  #pragma unroll
  for (int i = 0; i < 4; ++i)
    #pragma unroll
    for (int j = 0; j < 4; ++j) acc[i][j] = (f32x4){0.f, 0.f, 0.f, 0.f};

  bf16x8 a[4], b[4];
  #pragma unroll
  for (int mi = 0; mi < 4; ++mi) a[mi] = Ab[mi * 16];
  #pragma unroll
  for (int ni = 0; ni < 4; ++ni) b[ni] = Bb[ni * 16];

  for (int s = 0; s < 36; ++s) {
    bf16x8 an[4], bn[4];
    if (s < 35) {
      const bf16x8* An = Ab + (size_t)(s + 1) * 4 * 512;
      const bf16x8* Bn = Bb + (size_t)(s + 1) * 4 * NTASK;
      #pragma unroll
      for (int mi = 0; mi < 4; ++mi) an[mi] = An[mi * 16];
      #pragma unroll
      for (int ni = 0; ni < 4; ++ni) bn[ni] = Bn[ni * 16];
    }
    #pragma unroll
    for (int mi = 0; mi < 4; ++mi)
      #pragma unroll
      for (int ni = 0; ni < 4; ++ni)
        acc[mi][ni] = __builtin_amdgcn_mfma_f32_16x16x32_bf16(a[mi], b[ni], acc[mi][ni], 0, 0, 0);
    if (s < 35) {
      #pragma unroll
      for (int mi = 0; mi < 4; ++mi) a[mi] = an[mi];
      #pragma unroll
      for (int ni = 0; ni < 4; ++ni) b[ni] = bn[ni];
    }
  }
  size_t hb = (size_t)wave * NTASK;
  #pragma unroll
  for (int mi = 0; mi < 4; ++mi) {
    int c = c0 + mi * 16 + quad * 4;
    #pragma unroll
    for (int ni = 0; ni < 4; ++ni) {
      int t = tt0 + ni * 16 + r;
      *(f32x4*)(H4 + (hb + t) * 512 + c) = acc[mi][ni];
    }
  }
}

// epilogue: 4 tasks per 256-thr block (wave per task)
__global__ __launch_bounds__(256) void k_out(const float* __restrict__ H4,
    const int* __restrict__ tasks,
    const float* __restrict__ cb, const float* __restrict__ bw,
    const float* __restrict__ bb, const float* __restrict__ sw,
    const float* __restrict__ sb, float* __restrict__ outv) {
  int wave = threadIdx.x >> 6, lane = threadIdx.x & 63;
  int t = blockIdx.x * 4 + wave;
  int rec = tasks[t];
  if (rec >= 0) return;                        // wave-uniform
  int wr = (rec >> 16) & 63;
  const float* wrow = (wr < 36) ? (bw + wr * 512) : (sw + (wr - 36) * 512);
  float s = 0.0f;
  #pragma unroll
  for (int it = 0; it < 8; ++it) {
    int c = it * 64 + lane;
    size_t o = (size_t)t * 512 + c;
    float hv = H4[o] + H4[o + 1280 * 512] + H4[o + 2 * 1280 * 512] + H4[o + 3 * 1280 * 512] + cb[c];
    s = fmaf(fmaxf(hv, 0.0f), wrow[c], s);
  }
  #pragma unroll
  for (int off = 32; off > 0; off >>= 1) s += __shfl_down(s, off);
  if (lane == 0) {
    float b = (wr < 36) ? bb[wr] : sb[wr - 36];
    outv[t] = fmaxf(s + b, 0.0f);
  }
}

__global__ __launch_bounds__(256) void k_loss(const float* __restrict__ outv,
    const float* __restrict__ treg, const int* __restrict__ nposp,
    float* __restrict__ out) {
  __shared__ float r1[256], r2[256];
  int tid = threadIdx.x;
  int np = *nposp;
  float ce = 0.0f;
  for (int r = tid; r < 384; r += 256) {
    bool valid = (r < 128) ? (r < np) : ((r - 128) < 256 - np);
    if (valid) {
      int t0 = (r < 128) ? (r * 6 + 4) : (768 + 2 * (r - 128));
      float s0 = outv[t0], s1 = outv[t0 + 1];
      float mm = fmaxf(s0, s1);
      float lse = mm + logf(expf(s0 - mm) + expf(s1 - mm));
      ce += lse - ((r < 128) ? s0 : s1);
    }
  }
  float rg = 0.0f;
  for (int r = tid; r < 512; r += 256) {
    if ((r >> 2) < np) {
      float d = outv[(r >> 2) * 6 + (r & 3)] - treg[r];
      float ad = fabsf(d);
      rg += (ad < 1.0f) ? 0.5f * d * d : ad - 0.5f;
    }
  }
  r1[tid] = ce; r2[tid] = rg;
  __syncthreads();
  for (int s = 128; s > 0; s >>= 1) {
    if (tid < s) { r1[tid] += r1[tid + s]; r2[tid] += r2[tid + s]; }
    __syncthreads();
  }
  if (tid == 0) {
    float score_loss = r1[0] / 256.0f;                       // sum(valid) == 256 always
    float reg_loss = r2[0] / fmaxf(4.0f * (float)np, 1.0f);
    out[0] = score_loss + 10.0f * reg_loss;
  }
}

extern "C" void kernel_launch(void* const* d_in, const int* in_sizes, int n_in,
                              void* d_out, int out_size, void* d_ws, size_t ws_size,
                              hipStream_t stream) {
  const float* x   = (const float*)d_in[0];
  const float* tgt = (const float*)d_in[1];
  const float* cw  = (const float*)d_in[2];
  const float* cb  = (const float*)d_in[3];
  const float* bw  = (const float*)d_in[4];
  const float* bb  = (const float*)d_in[5];
  const float* sw  = (const float*)d_in[6];
  const float* sb  = (const float*)d_in[7];
  const int* imh   = (const int*)d_in[8];
  const int* imw   = (const int*)d_in[9];

  char* ws = (char*)d_ws;
  unsigned short* Wb2 = (unsigned short*)(ws + OFF_WB2);
  unsigned short* P2  = (unsigned short*)(ws + OFF_P2);
  float* H4    = (float*)(ws + OFF_H4);
  float* miou  = (float*)(ws + OFF_MIOU);
  ull*   cand  = (ull*)(ws + OFF_CAND);
  int*   cpb   = (int*)(ws + OFF_CPB);
  int*   cbz   = (int*)(ws + OFF_CBZ);
  int*   nposp = (int*)(ws + OFF_NPOS);
  float* treg  = (float*)(ws + OFF_TREG);
  int*   tasks = (int*)(ws + OFF_TASKS);
  int*   runs  = (int*)(ws + OFF_RUNS);
  float* outv  = (float*)(ws + OFF_OUT);
  float* out   = (float*)d_out;

  k_pi    <<<dim3(NIOUB + NPREPB), dim3(256), 0, stream>>>(cw, Wb2, tgt, imw, imh, miou, cand, cpb, cbz);
  k_sel   <<<dim3(1),              dim3(256), 0, stream>>>(miou, cand, cpb, cbz, tgt, imw, imh, nposp, treg, tasks, runs);
  k_gather<<<dim3(512),            dim3(256), 0, stream>>>(x, runs, P2);
  k_mfma  <<<dim3(20, 8),          dim3(256), 0, stream>>>(Wb2, P2, nposp, H4);
  k_out   <<<dim3(320),            dim3(256), 0, stream>>>(H4, tasks, cb, bw, bb, sw, sb, outv);
  k_loss  <<<dim3(1),              dim3(256), 0, stream>>>(outv, treg, nposp, out);
}

// Round 9
// 166.897 us; speedup vs baseline: 1.0777x; 1.0777x over previous
//
#include <hip/hip_runtime.h>
#include <cstdint>
#include <cstddef>

typedef unsigned long long ull;
typedef __bf16 bf16x8 __attribute__((ext_vector_type(8)));
typedef float f32x4 __attribute__((ext_vector_type(4)));

#define NA     147456   // 128*128*9 anchors
#define NT     64       // targets
#define KDIM   4608     // 512*9 reduction
#define NTASK  1280     // 128*6 + 256*2 output-value tasks
#define CAND_CAP 4096
#define KSPLIT 4
#define NIOUB  576      // iou blocks (k_pi [0,576))
#define NTRB   2048     // transpose blocks (k_pi [576,2624))
#define NPREP2 512      // prep blocks, one per cout row (k_pi [2624,3136))
#define NIMCB  2880     // im2col blocks

// ---- workspace byte offsets (~45.6 MB) ----
#define OFF_WB2   0           // ushort[576*512*8]  bf16 weights, frag-native [kc][m][8], k = r*512+cin
#define OFF_P2    4718592     // ushort[576*1280*8] bf16 im2col,  frag-native [kc][t][8]
#define OFF_H4    16515072    // float[4][1280][512] K-split partial h, task-major
#define OFF_XT    27000832    // ushort[16384][512] bf16 NHWC transpose of x (16.78 MB)
#define OFF_MIOU  43778048    // float[147456]
#define OFF_CAND  44367872    // ull[576*256] block-local candidate lists
#define OFF_CPB   45547520    // int[576] per-block candidate counts
#define OFF_CBZ   45549824    // int[576] per-block zero-iou counts
#define OFF_NPOS  45552128    // int
#define OFF_POSA  45552132    // int[128]
#define OFF_TREG  45552648    // float[512]
#define OFF_TASKS 45554696    // int[1280]
#define OFF_OUT   45559816    // float[1280]

// anchor w/h table; U = sqrt(128*128/2); power-of-2 multiples are exact in fp32.
#define UANC 90.509667991878f
__device__ __constant__ float WKa[9] = {128.0f, 2.0f*UANC, UANC, 256.0f, 4.0f*UANC, 2.0f*UANC, 512.0f, 8.0f*UANC, 4.0f*UANC};
__device__ __constant__ float HKa[9] = {128.0f, UANC, 2.0f*UANC, 256.0f, 2.0f*UANC, 4.0f*UANC, 512.0f, 4.0f*UANC, 8.0f*UANC};

__device__ __forceinline__ float iou_one(float x1, float y1, float x2, float y2, float4 t) {
#pragma clang fp contract(off)
  float ltx = fmaxf(t.x, x1), lty = fmaxf(t.y, y1);
  float rbx = fminf(t.z, x2), rby = fminf(t.w, y2);
  float wx = fmaxf(rbx - ltx, 0.0f);
  float wy = fmaxf(rby - lty, 0.0f);
  float inter = wx * wy;
  float at = (t.z - t.x) * (t.w - t.y);
  float aa = (x2 - x1) * (y2 - y1);
  return inter / ((at + aa) - inter);
}

__device__ __forceinline__ unsigned short f2bf(float f) {
  unsigned int u = __float_as_uint(f);
  unsigned int r = (u + 0x7fffu + ((u >> 16) & 1u)) >> 16;
  return (unsigned short)r;
}

// three-role kernel, all selection-independent work:
//   [0,576):     IoU + per-block candidate/zero stats
//   [576,2624):  x NCHW fp32 -> NHWC bf16 transpose (64x64 LDS tile)
//   [2624,3136): weight repack, LDS-staged: coalesced row load -> frag scatter
__global__ __launch_bounds__(256) void k_pi(const float* __restrict__ cw,
    unsigned short* __restrict__ Wb2, const float* __restrict__ x,
    unsigned short* __restrict__ xtb,
    const float* __restrict__ tgt, const int* __restrict__ imw,
    const int* __restrict__ imh, float* __restrict__ miou,
    ull* __restrict__ cand, int* __restrict__ cpb, int* __restrict__ cbz) {
  __shared__ __align__(16) char smem[20480];
  int blk = blockIdx.x;
  int tid = threadIdx.x;
  if (blk >= NIOUB + NTRB) {                   // ---- prep: one cout row, LDS-staged ----
    float* row = (float*)smem;                 // padded [cin*10 + r], 20480 B
    int m = blk - (NIOUB + NTRB);
    const float* src = cw + (size_t)m * KDIM;
    for (int f = tid; f < KDIM; f += 256) {
      int cin = f / 9;
      row[cin * 10 + (f - cin * 9)] = src[f];  // coalesced global read
    }
    __syncthreads();
    for (int kc = tid; kc < 576; kc += 256) {
      int r = kc >> 6, c8 = kc & 63;
      int base = c8 * 80 + r;
      unsigned short o[8];
      #pragma unroll
      for (int j = 0; j < 8; ++j) o[j] = f2bf(row[base + j * 10]);
      *(uint4*)(Wb2 + ((size_t)kc * 512 + m) * 8) = *(const uint4*)o;
    }
    return;
  }
  if (blk >= NIOUB) {                          // ---- transpose 64pix x 64cin, bf16 out ----
    float* tile = (float*)smem;                // [64][65] (16640 <= 20480)
    int tb = blk - NIOUB;
    int pix0 = (tb & 255) * 64;
    int cin0 = (tb >> 8) * 64;
    int pr = tid & 15, cr = tid >> 4;
    #pragma unroll
    for (int i = 0; i < 4; ++i) {
      int cin = cr + i * 16;
      float4 v = *(const float4*)(x + (size_t)(cin0 + cin) * 16384 + pix0 + pr * 4);
      tile[cin * 65 + pr * 4 + 0] = v.x;
      tile[cin * 65 + pr * 4 + 1] = v.y;
      tile[cin * 65 + pr * 4 + 2] = v.z;
      tile[cin * 65 + pr * 4 + 3] = v.w;
    }
    __syncthreads();
    #pragma unroll
    for (int i = 0; i < 4; ++i) {              // write: lanes along cin, bf16x4 (8B)
      int pix = cr + i * 16;
      unsigned short o[4] = {f2bf(tile[(pr * 4 + 0) * 65 + pix]),
                             f2bf(tile[(pr * 4 + 1) * 65 + pix]),
                             f2bf(tile[(pr * 4 + 2) * 65 + pix]),
                             f2bf(tile[(pr * 4 + 3) * 65 + pix])};
      *(uint2*)(xtb + (size_t)(pix0 + pix) * 512 + cin0 + pr * 4) = *(const uint2*)o;
    }
    return;
  }
  // ---- IoU ----
  float4* ts = (float4*)smem;                  // [64]
  int* wz = (int*)(smem + 1024);
  int* wc = wz + 4;
  if (tid < NT) ts[tid] = ((const float4*)tgt)[tid];
  __syncthreads();
  int a = blk * 256 + tid;
  int k = a % 9;
  int pq = a / 9;
  int p = pq >> 7, q = pq & 127;
  float dx = (float)(*imw) / 127.0f;
  float dyl = (float)(*imh) / 127.0f;
  float x1 = (float)p * dx, y1 = (float)q * dyl;
  float x2 = x1 + WKa[k], y2 = y1 + HKa[k];
  float best = -1.0f;
  #pragma unroll 8
  for (int t = 0; t < NT; ++t) best = fmaxf(best, iou_one(x1, y1, x2, y2, ts[t]));
  miou[a] = best;
  int lane = tid & 63, w = tid >> 6;
  ull bz = __ballot(best == 0.0f);
  bool isc = best > 0.7f;
  ull bc = __ballot(isc);
  if (lane == 0) { wz[w] = (int)__popcll(bz); wc[w] = (int)__popcll(bc); }
  __syncthreads();
  if (tid == 0) {
    cbz[blk] = wz[0] + wz[1] + wz[2] + wz[3];
    cpb[blk] = wc[0] + wc[1] + wc[2] + wc[3];
  }
  if (isc) {
    int woff = 0;
    for (int i = 0; i < w; ++i) woff += wc[i];
    int rank = woff + (int)__popcll(bc & ((1ull << lane) - 1ull));
    cand[blk * 256 + rank] = ((ull)__float_as_uint(best) << 32) | (ull)(0xFFFFFFFFu - (unsigned)a);
  }
}

// single block: pos top-128 SET via radix-select (histogram + boundary-bin sort).
// key = (iou_bits<<32)|~idx; bin = (iou_bits-0x3F333334)>>13 in [0,614].
__global__ __launch_bounds__(256) void k_selA(const ull* __restrict__ cand,
    const int* __restrict__ cpb, int* __restrict__ nposp, int* __restrict__ posa) {
  __shared__ ull keys[CAND_CAP];               // 32 KB
  __shared__ ull bnd[1024];                    // 8 KB
  __shared__ int hist[1024];                   // 4 KB
  __shared__ int cpbL[576];
  __shared__ int base576[577];
  __shared__ int wtot[4];
  __shared__ int selCnt, bndCnt, Tbin, mAbove;
  int tid = threadIdx.x;
  int lane = tid & 63;
  for (int i = tid; i < 576; i += 256) cpbL[i] = cpb[i];
  for (int i = tid; i < 1024; i += 256) hist[i] = 0;
  __syncthreads();
  // exclusive prefix over cpbL[576]: 192 threads x 3 elems + wave scan
  int e0 = 0, e1 = 0, sA = 0, scanA = 0;
  if (tid < 192) {
    e0 = cpbL[3 * tid]; e1 = cpbL[3 * tid + 1]; int e2 = cpbL[3 * tid + 2];
    sA = e0 + e1 + e2;
    scanA = sA;
    for (int off = 1; off < 64; off <<= 1) {
      int v = __shfl_up(scanA, off);
      if (lane >= off) scanA += v;
    }
    if (lane == 63) wtot[tid >> 6] = scanA;
  }
  __syncthreads();
  if (tid < 192) {
    int w = tid >> 6;
    int woff = 0;
    for (int i = 0; i < w; ++i) woff += wtot[i];
    int excl = woff + scanA - sA;
    base576[3 * tid]     = excl;
    base576[3 * tid + 1] = excl + e0;
    base576[3 * tid + 2] = excl + e0 + e1;
    if (tid == 191) base576[576] = excl + sA;
  }
  __syncthreads();
  int cnt = base576[576]; if (cnt > CAND_CAP) cnt = CAND_CAP;
  for (int i = tid; i < CAND_CAP; i += 256) if (i >= cnt) keys[i] = 0ull;
  // load-balanced compaction: rank -> (block,entry) via binary search
  for (int rk = tid; rk < cnt; rk += 256) {
    int lo = 0, hi = 576;
    while (hi - lo > 1) { int mid = (lo + hi) >> 1; if (base576[mid] <= rk) lo = mid; else hi = mid; }
    keys[rk] = cand[lo * 256 + (rk - base576[lo])];
  }
  __syncthreads();
  if (cnt <= 128) {                            // set-invariant: slot order irrelevant
    if (tid < cnt) posa[tid] = (int)(0xFFFFFFFFu - (unsigned)(keys[tid] & 0xFFFFFFFFull));
    if (tid == 0) *nposp = cnt;
    return;
  }
  // histogram
  for (int i = tid; i < cnt; i += 256) {
    unsigned ib = (unsigned)(keys[i] >> 32);
    atomicAdd(&hist[(ib - 0x3F333334u) >> 13], 1);
  }
  __syncthreads();
  // wave 0: coarse suffix scan (64 groups x 16 bins) -> threshold bin T
  if (tid < 64) {
    int s = 0;
    #pragma unroll
    for (int t = 0; t < 16; ++t) s += hist[tid * 16 + t];
    int S = s;
    #pragma unroll
    for (int off = 1; off < 64; off <<= 1) {
      int u = __shfl_down(S, off);
      if (tid + off < 64) S += u;
    }
    ull mask = __ballot(S >= 128);             // nonzero: S[0] = cnt >= 129
    int g = 63 - __clzll(mask);                // largest group with suffix >= 128
    int aboveS = __shfl(S, (g + 1 < 64) ? g + 1 : 63);
    if (g == 63) aboveS = 0;
    if (tid == 0) {
      int run = aboveS, T = g * 16 + 15;
      for (int b = g * 16 + 15; b >= g * 16; --b) {
        int h = hist[b];
        if (run + h >= 128) { T = b; break; }
        run += h;
      }
      Tbin = T; mAbove = run; selCnt = 0; bndCnt = 0;
    }
  }
  __syncthreads();
  int T = Tbin, m = mAbove;
  for (int i = tid; i < cnt; i += 256) {
    ull kk = keys[i];
    unsigned ib = (unsigned)(kk >> 32);
    int b = (int)((ib - 0x3F333334u) >> 13);
    if (b > T) {
      int r = atomicAdd(&selCnt, 1);
      posa[r] = (int)(0xFFFFFFFFu - (unsigned)(kk & 0xFFFFFFFFull));
    } else if (b == T) {
      int r = atomicAdd(&bndCnt, 1);
      if (r < 1024) bnd[r] = kk;
    }
  }
  __syncthreads();
  int B = bndCnt;
  int need = 128 - m;
  if (B <= 1024) {
    int n2 = 2; while (n2 < B) n2 <<= 1;
    for (int i = tid; i < n2; i += 256) if (i >= B) bnd[i] = 0ull;
    for (int size = 2; size <= n2; size <<= 1)
      for (int stride = size >> 1; stride > 0; stride >>= 1) {
        __syncthreads();
        for (int t = tid; t < n2 / 2; t += 256) {
          int i = 2 * t - (t & (stride - 1));
          int j = i + stride;
          ull a = bnd[i], b2 = bnd[j];
          bool desc = ((i & size) == 0);
          if (desc ? (a < b2) : (a > b2)) { bnd[i] = b2; bnd[j] = a; }
        }
      }
    __syncthreads();
    if (tid < need) posa[m + tid] = (int)(0xFFFFFFFFu - (unsigned)(bnd[tid] & 0xFFFFFFFFull));
  } else {                                     // pathological tie storm: full sort fallback
    for (int size = 2; size <= CAND_CAP; size <<= 1)
      for (int stride = size >> 1; stride > 0; stride >>= 1) {
        __syncthreads();
        for (int t = tid; t < CAND_CAP / 2; t += 256) {
          int i = 2 * t - (t & (stride - 1));
          int j = i + stride;
          ull a = keys[i], b2 = keys[j];
          bool desc = ((i & size) == 0);
          if (desc ? (a < b2) : (a > b2)) { keys[i] = b2; keys[j] = a; }
        }
      }
    __syncthreads();
    if (tid < 128) posa[tid] = (int)(0xFFFFFFFFu - (unsigned)(keys[tid] & 0xFFFFFFFFull));
  }
  if (tid == 0) *nposp = 128;
}

// single block: neg-select + treg + task table
__global__ __launch_bounds__(256) void k_selB(const float* __restrict__ miou,
    const int* __restrict__ cbz, const float* __restrict__ tgt,
    const int* __restrict__ imw, const int* __restrict__ imh,
    const int* __restrict__ nposp, const int* __restrict__ posa,
    float* __restrict__ treg, int* __restrict__ tasks) {
  __shared__ int nzbase[145];
  __shared__ float4 ts[NT];
  __shared__ int posi[128];
  __shared__ int negA[256];
  __shared__ int wsum[4];
  int tid = threadIdx.x;
  int lane = tid & 63;
  if (tid < NT) ts[tid] = ((const float4*)tgt)[tid];
  int np = *nposp;
  if (tid < np) posi[tid] = posa[tid];
  // scan of per-1024-chunk zero counts, 144 threads
  int sB = 0, scanB = 0;
  if (tid < 144) {
    int4 cz4 = *(const int4*)(cbz + 4 * tid);
    sB = cz4.x + cz4.y + cz4.z + cz4.w;
    scanB = sB;
    for (int off = 1; off < 64; off <<= 1) {
      int v = __shfl_up(scanB, off);
      if (lane >= off) scanB += v;
    }
    bool last = (tid < 128) ? (lane == 63) : (tid == 143);
    if (last) wsum[tid >> 6] = scanB;
  }
  __syncthreads();
  if (tid < 144) {
    int w = tid >> 6;
    int woff = 0;
    for (int i = 0; i < w; ++i) woff += wsum[i];
    nzbase[tid] = woff + scanB - sB;
    if (tid == 143) nzbase[144] = woff + scanB;
  }
  __syncthreads();
  // neg select: first 256 zero-iou anchors by index
  int w = tid >> 6;
  for (int j = 0; j < 144; ++j) {
    if (nzbase[j] >= 256) break;               // uniform
    int a0 = j * 1024 + tid * 4;
    float4 m4 = *(const float4*)(miou + a0);
    int f0 = (m4.x == 0.0f), f1 = (m4.y == 0.0f), f2 = (m4.z == 0.0f), f3 = (m4.w == 0.0f);
    int tsum = f0 + f1 + f2 + f3;
    int scan = tsum;
    for (int off = 1; off < 64; off <<= 1) {
      int v = __shfl_up(scan, off);
      if (lane >= off) scan += v;
    }
    if (lane == 63) wsum[w] = scan;
    __syncthreads();
    int woff = nzbase[j];
    for (int i = 0; i < w; ++i) woff += wsum[i];
    int r = woff + scan - tsum;
    if (f0) { if (r < 256) negA[r] = a0;     r++; }
    if (f1) { if (r < 256) negA[r] = a0 + 1; r++; }
    if (f2) { if (r < 256) negA[r] = a0 + 2; r++; }
    if (f3) { if (r < 256) negA[r] = a0 + 3;      }
    __syncthreads();
  }
  __syncthreads();
  // treg for pos anchors
  if (tid < np) {
    int a = posi[tid];
    int k = a % 9; int pq = a / 9; int p = pq >> 7, q = pq & 127;
    float dx = (float)(*imw) / 127.0f, dyl = (float)(*imh) / 127.0f;
    float x1 = (float)p * dx, y1 = (float)q * dyl;
    float x2 = x1 + WKa[k], y2 = y1 + HKa[k];
    float best = -1.0f; int bt = 0;
    for (int t = 0; t < NT; ++t) {
      float v = iou_one(x1, y1, x2, y2, ts[t]);
      if (v > best) { best = v; bt = t; }      // first-max == jnp.argmax
    }
    float4 m = ts[bt];
    float aw = x2 - x1, ah = y2 - y1;
    float acx = x1 + aw * 0.5f, acy = y1 + ah * 0.5f;
    float bwd = m.z - m.x, bhd = m.w - m.y;
    float bcx = m.x + bwd * 0.5f, bcy = m.y + bhd * 0.5f;
    treg[tid * 4 + 0] = (bcx - acx) / aw;
    treg[tid * 4 + 1] = (bcy - acy) / ah;
    treg[tid * 4 + 2] = logf(bwd / aw);
    treg[tid * 4 + 3] = logf(bhd / ah);
  }
  // task table
  for (int t = tid; t < NTASK; t += 256) {
    int rec = 0;
    if (t < 768) {
      int s = t / 6, jj = t - s * 6;
      if (s < np) {
        int a = posi[s];
        int f, wr, xx;
        if (jj < 4) { f = 4 * a; wr = f >> 14; xx = (f & 127) + jj; }
        else        { f = 2 * a; wr = 36 + (f >> 14); xx = (f & 127) + (jj - 4); }
        int yy = (f >> 7) & 127;
        rec = (int)(0x80000000u | ((unsigned)wr << 16) | ((unsigned)yy << 8) | (unsigned)xx);
      }
    } else {
      int s = (t - 768) >> 1, jj = (t - 768) & 1;
      if (s < 256 - np) {
        int a = negA[s];
        int f = 2 * a; int wr = 36 + (f >> 14); int yy = (f >> 7) & 127; int xx = (f & 127) + jj;
        rec = (int)(0x80000000u | ((unsigned)wr << 16) | ((unsigned)yy << 8) | (unsigned)xx);
      }
    }
    tasks[t] = rec;
  }
}

// im2col from bf16 NHWC x_t: pure 16B fragment relabeling copy. P2[kc][t][8].
__global__ __launch_bounds__(256) void k_im2col(const unsigned short* __restrict__ xtb,
    const int* __restrict__ tasks, unsigned short* __restrict__ P2) {
  int idx = blockIdx.x * 256 + threadIdx.x;    // 1280*576 = 737280
  int t = idx / 576;
  int kc = idx - t * 576;
  int r = kc >> 6, c8 = kc & 63;               // k = r*512+cin
  int rec = tasks[t];
  uint4 frag = {0u, 0u, 0u, 0u};
  if (rec < 0) {
    int py = (rec >> 8) & 127, px = rec & 127;
    int dy = r / 3;
    int yy = py + dy - 1, xx = px + (r - dy * 3) - 1;
    if (yy >= 0 && yy < 128 && xx >= 0 && xx < 128)
      frag = *(const uint4*)(xtb + (size_t)(yy * 128 + xx) * 512 + c8 * 8);
  }
  *(uint4*)(P2 + ((size_t)kc * NTASK + t) * 8) = frag;
}

// LDS-free bf16 MFMA GEMM (R7 known-good: 128x128 block tile, K-split on z)
__global__ __launch_bounds__(256) void k_mfma(const unsigned short* __restrict__ Wb2,
    const unsigned short* __restrict__ P2, const int* __restrict__ nposp,
    float* __restrict__ H4) {
  int npos = *nposp;
  int tt0 = blockIdx.x * 128;
  int posend = 6 * npos, negend = 768 + 2 * (256 - npos);
  if (!((tt0 < posend) || ((tt0 + 128 > 768) && (tt0 < negend)))) return;
  int c0 = blockIdx.y * 128;
  int ks = blockIdx.z;
  int tid = threadIdx.x;
  int wave = tid >> 6, lane = tid & 63;
  int quad = lane >> 4, r = lane & 15;
  int m_base = c0 + (wave & 1) * 64;
  int n_base = tt0 + (wave >> 1) * 64;
  int kc0 = ks * 144 + quad;
  const bf16x8* Ab = (const bf16x8*)Wb2 + ((size_t)kc0 * 512 + m_base + r);
  const bf16x8* Bb = (const bf16x8*)P2 + ((size_t)kc0 * NTASK + n_base + r);

  f32x4 acc[4][4];
  #pragma unroll
  for (int i = 0; i < 4; ++i)
    #pragma unroll
    for (int j = 0; j < 4; ++j) acc[i][j] = (f32x4){0.f, 0.f, 0.f, 0.f};

  bf16x8 a[4], b[4];
  #pragma unroll
  for (int mi = 0; mi < 4; ++mi) a[mi] = Ab[mi * 16];
  #pragma unroll
  for (int ni = 0; ni < 4; ++ni) b[ni] = Bb[ni * 16];

  for (int s = 0; s < 36; ++s) {
    bf16x8 an[4], bn[4];
    if (s < 35) {
      const bf16x8* An = Ab + (size_t)(s + 1) * 4 * 512;
      const bf16x8* Bn = Bb + (size_t)(s + 1) * 4 * NTASK;
      #pragma unroll
      for (int mi = 0; mi < 4; ++mi) an[mi] = An[mi * 16];
      #pragma unroll
      for (int ni = 0; ni < 4; ++ni) bn[ni] = Bn[ni * 16];
    }
    #pragma unroll
    for (int mi = 0; mi < 4; ++mi)
      #pragma unroll
      for (int ni = 0; ni < 4; ++ni)
        acc[mi][ni] = __builtin_amdgcn_mfma_f32_16x16x32_bf16(a[mi], b[ni], acc[mi][ni], 0, 0, 0);
    if (s < 35) {
      #pragma unroll
      for (int mi = 0; mi < 4; ++mi) a[mi] = an[mi];
      #pragma unroll
      for (int ni = 0; ni < 4; ++ni) b[ni] = bn[ni];
    }
  }
  size_t hb = (size_t)ks * NTASK;
  #pragma unroll
  for (int mi = 0; mi < 4; ++mi) {
    int c = m_base + mi * 16 + quad * 4;
    #pragma unroll
    for (int ni = 0; ni < 4; ++ni) {
      int t = n_base + ni * 16 + r;
      *(f32x4*)(H4 + (hb + t) * 512 + c) = acc[mi][ni];
    }
  }
}

// epilogue: 4 tasks per 256-thr block (wave per task)
__global__ __launch_bounds__(256) void k_out(const float* __restrict__ H4,
    const int* __restrict__ tasks,
    const float* __restrict__ cb, const float* __restrict__ bw,
    const float* __restrict__ bb, const float* __restrict__ sw,
    const float* __restrict__ sb, float* __restrict__ outv) {
  int wave = threadIdx.x >> 6, lane = threadIdx.x & 63;
  int t = blockIdx.x * 4 + wave;
  int rec = tasks[t];
  if (rec >= 0) return;                        // wave-uniform
  int wr = (rec >> 16) & 63;
  const float* wrow = (wr < 36) ? (bw + wr * 512) : (sw + (wr - 36) * 512);
  float s = 0.0f;
  #pragma unroll
  for (int it = 0; it < 8; ++it) {
    int c = it * 64 + lane;
    size_t o = (size_t)t * 512 + c;
    float hv = H4[o] + H4[o + 1280 * 512] + H4[o + 2 * 1280 * 512] + H4[o + 3 * 1280 * 512] + cb[c];
    s = fmaf(fmaxf(hv, 0.0f), wrow[c], s);
  }
  #pragma unroll
  for (int off = 32; off > 0; off >>= 1) s += __shfl_down(s, off);
  if (lane == 0) {
    float b = (wr < 36) ? bb[wr] : sb[wr - 36];
    outv[t] = fmaxf(s + b, 0.0f);
  }
}

__global__ __launch_bounds__(256) void k_loss(const float* __restrict__ outv,
    const float* __restrict__ treg, const int* __restrict__ nposp,
    float* __restrict__ out) {
  __shared__ float r1[256], r2[256];
  int tid = threadIdx.x;
  int np = *nposp;
  float ce = 0.0f;
  for (int r = tid; r < 384; r += 256) {
    bool valid = (r < 128) ? (r < np) : ((r - 128) < 256 - np);
    if (valid) {
      int t0 = (r < 128) ? (r * 6 + 4) : (768 + 2 * (r - 128));
      float s0 = outv[t0], s1 = outv[t0 + 1];
      float mm = fmaxf(s0, s1);
      float lse = mm + logf(expf(s0 - mm) + expf(s1 - mm));
      ce += lse - ((r < 128) ? s0 : s1);
    }
  }
  float rg = 0.0f;
  for (int r = tid; r < 512; r += 256) {
    if ((r >> 2) < np) {
      float d = outv[(r >> 2) * 6 + (r & 3)] - treg[r];
      float ad = fabsf(d);
      rg += (ad < 1.0f) ? 0.5f * d * d : ad - 0.5f;
    }
  }
  r1[tid] = ce; r2[tid] = rg;
  __syncthreads();
  for (int s = 128; s > 0; s >>= 1) {
    if (tid < s) { r1[tid] += r1[tid + s]; r2[tid] += r2[tid + s]; }
    __syncthreads();
  }
  if (tid == 0) {
    float score_loss = r1[0] / 256.0f;                       // sum(valid) == 256 always
    float reg_loss = r2[0] / fmaxf(4.0f * (float)np, 1.0f);
    out[0] = score_loss + 10.0f * reg_loss;
  }
}

extern "C" void kernel_launch(void* const* d_in, const int* in_sizes, int n_in,
                              void* d_out, int out_size, void* d_ws, size_t ws_size,
                              hipStream_t stream) {
  const float* x   = (const float*)d_in[0];
  const float* tgt = (const float*)d_in[1];
  const float* cw  = (const float*)d_in[2];
  const float* cb  = (const float*)d_in[3];
  const float* bw  = (const float*)d_in[4];
  const float* bb  = (const float*)d_in[5];
  const float* sw  = (const float*)d_in[6];
  const float* sb  = (const float*)d_in[7];
  const int* imh   = (const int*)d_in[8];
  const int* imw   = (const int*)d_in[9];

  char* ws = (char*)d_ws;
  unsigned short* Wb2 = (unsigned short*)(ws + OFF_WB2);
  unsigned short* P2  = (unsigned short*)(ws + OFF_P2);
  float* H4    = (float*)(ws + OFF_H4);
  unsigned short* xtb = (unsigned short*)(ws + OFF_XT);
  float* miou  = (float*)(ws + OFF_MIOU);
  ull*   cand  = (ull*)(ws + OFF_CAND);
  int*   cpb   = (int*)(ws + OFF_CPB);
  int*   cbz   = (int*)(ws + OFF_CBZ);
  int*   nposp = (int*)(ws + OFF_NPOS);
  int*   posa  = (int*)(ws + OFF_POSA);
  float* treg  = (float*)(ws + OFF_TREG);
  int*   tasks = (int*)(ws + OFF_TASKS);
  float* outv  = (float*)(ws + OFF_OUT);
  float* out   = (float*)d_out;

  k_pi    <<<dim3(NIOUB + NTRB + NPREP2), dim3(256), 0, stream>>>(cw, Wb2, x, xtb, tgt, imw, imh, miou, cand, cpb, cbz);
  k_selA  <<<dim3(1),             dim3(256), 0, stream>>>(cand, cpb, nposp, posa);
  k_selB  <<<dim3(1),             dim3(256), 0, stream>>>(miou, cbz, tgt, imw, imh, nposp, posa, treg, tasks);
  k_im2col<<<dim3(NIMCB),         dim3(256), 0, stream>>>(xtb, tasks, P2);
  k_mfma  <<<dim3(10, 4, KSPLIT), dim3(256), 0, stream>>>(Wb2, P2, nposp, H4);
  k_out   <<<dim3(320),           dim3(256), 0, stream>>>(H4, tasks, cb, bw, bb, sw, sb, outv);
  k_loss  <<<dim3(1),             dim3(256), 0, stream>>>(outv, treg, nposp, out);
}